// Round 5
// baseline (672.381 us; speedup 1.0000x reference)
//
#include <hip/hip_runtime.h>
#include <math.h>

// Problem constants
#define BB   128
#define LL   512
#define CC   321
#define PREDD 336
// Seasonal MLP: rows = B*C*S = 164352, dims 128 -> 512 -> 128 (x2 blocks)

using bf16x8  = __attribute__((ext_vector_type(8))) __bf16;
using floatx4 = __attribute__((ext_vector_type(4))) float;
using uintx4  = __attribute__((ext_vector_type(4))) unsigned int;
typedef unsigned short u16;

#define MFMA16(a,b,c) __builtin_amdgcn_mfma_f32_16x16x32_bf16(a,b,c,0,0,0)

__device__ __forceinline__ u16 f2bf(float f){
    union { float f; unsigned u; } v; v.f = f;
    unsigned r = v.u + 0x7FFFu + ((v.u >> 16) & 1u);   // RNE
    return (u16)(r >> 16);
}

// tanh-GELU via exp2: max |err| vs exact erf-GELU ~3e-4 << bf16 rounding.
__device__ __forceinline__ float fgelu(float x){
    float u = x*(0.7978845608f + 0.035677408f*x*x);
    float a = fminf(u*2.8853900818f, 80.f);       // 2*log2(e)*u, clamp vs inf/inf
    float t = __builtin_amdgcn_exp2f(a);          // v_exp_f32
    return x*t*__builtin_amdgcn_rcpf(1.f + t);
}

// XOR-segment swizzle: tiles stored unpadded; 16B segment s of row r lives at
// s' = (s&8)|((s^r)&7). Every frag read / staging write pattern then hits the
// 2-way / floor bank pattern (2-way is free on gfx950, m136).
__device__ __forceinline__ int swz128(int r, int s){ return r*128 + (((s & 8) | ((s ^ r) & 7)) << 3); }
__device__ __forceinline__ int swz64 (int r, int s){ return r*64  + (((s ^ r) & 7) << 3); }

// ---------------- weight prep: fp32 -> bf16, pre-transposed [Ncols][K] ----------------
__global__ void prep_k(const float* __restrict__ W11, const float* __restrict__ W12,
                       const float* __restrict__ W21, const float* __restrict__ W22,
                       const float* __restrict__ Wtr, const float* __restrict__ Wse,
                       u16* __restrict__ BT1, u16* __restrict__ BT2,
                       u16* __restrict__ BT3, u16* __restrict__ BT4,
                       u16* __restrict__ BT5)
{
    int idx = blockIdx.x * 256 + threadIdx.x;
    if (idx < 65536){
        int h = idx >> 7, k = idx & 127;          // BT1/BT3: [512][128] = W11^T / W21^T
        BT1[idx] = f2bf(W11[k*512 + h]);
        BT3[idx] = f2bf(W21[k*512 + h]);
        int n = idx >> 9, k2 = idx & 511;         // BT2/BT4: [128][512] = W12^T / W22^T
        BT2[idx] = f2bf(W12[k2*128 + n]);
        BT4[idx] = f2bf(W22[k2*128 + n]);
    }
    if (idx < 393216){
        // BT5: [384][1024]; k<512 -> W_tr rows; k>=512 -> W_se rows permuted to (s,n)-major
        int p = idx >> 10, k = idx & 1023;
        float v = 0.f;
        if (p < PREDD){
            if (k < 512) v = Wtr[k*PREDD + p];
            else { int kk = k - 512; int s = kk >> 7; int n = kk & 127; v = Wse[(4*n + s)*PREDD + p]; }
        }
        BT5[idx] = f2bf(v);
    }
}

// ---------------- fused RevIN stats + moving-avg decomposition ----------------
#define XT(t,c) xt[((t)<<4) + (((t)>>5)<<1) + (c)]
__global__ __launch_bounds__(256) void decomp_k(
    const float* __restrict__ x, const float* __restrict__ rw, const float* __restrict__ rb,
    u16* __restrict__ Afin, u16* __restrict__ xs, float2* __restrict__ stats)
{
    __shared__ float xt[8240];
    __shared__ float red[2][16][16];
    __shared__ float sh_m[16], sh_istd[16];
    int b = blockIdx.x / 21, ct = blockIdx.x % 21;
    int tid = threadIdx.x;

    int cl = tid & 15, lp = tid >> 4;
    int c = ct*16 + cl;
    bool valid = c < CC;
    const float* xb = x + (size_t)b*LL*CC;
    float s = 0.f, q = 0.f;
    for (int i = 0; i < 32; ++i){
        int t = lp + 16*i;
        float v = valid ? xb[(size_t)t*CC + c] : 0.f;
        XT(t, cl) = v;
        s += v; q += v*v;
    }
    red[0][lp][cl] = s; red[1][lp][cl] = q;
    __syncthreads();
    if (tid < 16){
        float ss = 0.f, qq = 0.f;
        for (int j = 0; j < 16; ++j){ ss += red[0][j][tid]; qq += red[1][j][tid]; }
        float m  = ss * (1.f/512.f);
        float var = qq * (1.f/512.f) - m*m;
        float sd = sqrtf(var + 1e-5f);
        sh_m[tid] = m; sh_istd[tid] = 1.f/sd;
        int cc = ct*16 + tid;
        if (cc < CC) stats[(size_t)b*CC + cc] = make_float2(m, sd);
    }
    __syncthreads();

    int ch = tid >> 4, tp = tid & 15;
    int c2 = ct*16 + ch;
    if (c2 >= CC) return;
    float m = sh_m[ch], istd = sh_istd[ch];
    float w = rw[c2] * istd, bbv = rb[c2];
    size_t bc = (size_t)b*CC + c2;
    u16* tr  = Afin + bc*1024;
    u16* xsr = xs   + bc*512;
    int t0 = tp*32;

    float win = 0.f;
#pragma unroll
    for (int d = -12; d <= 12; ++d){
        int u = t0 + d; u = u < 0 ? 0 : (u > 511 ? 511 : u);
        win += XT(u, ch);
    }
    u16 trbuf[8];
    u16 xsbuf[4][8];
#pragma unroll
    for (int i = 0; i < 32; ++i){
        int t = t0 + i;
        float Ax = win * (1.f/25.f);
        float xv = XT(t, ch);
        trbuf[i & 7] = f2bf((Ax - m)*w + bbv);
        xsbuf[i & 3][i >> 2] = f2bf((xv - Ax)*w);
        if ((i & 7) == 7)
            *(uintx4*)(tr + t0 + (i & ~7)) = *(const uintx4*)trbuf;
        int uo = t - 12; uo = uo < 0 ? 0 : uo;
        int un = t + 13; un = un > 511 ? 511 : un;
        win += XT(un, ch) - XT(uo, ch);
    }
#pragma unroll
    for (int s4 = 0; s4 < 4; ++s4)
        *(uintx4*)(xsr + s4*128 + tp*8) = *(const uintx4*)xsbuf[s4];
}

// ---------------- fully fused 2-block MLP, software-pipelined ----------------
// LDS (u16 idx): Abuf [0,16384) = 128x128, overlays Hbuf0 [0,8192) + Hbuf1 [8192,16384)
//                W1buf [16384,24576) = 64x128;  W2buf slots [24576,32768),[32768,40960)
// Pipeline per mlp block: iter hc: S1 -> prefetch W[g+1] -> GEMM1[hc] -> GEMM2[hc-1]
//                          -> GELU[hc] -> S2 -> store regs->LDS.  2 syncs/iter.
#define W1B 16384
#define W2B 24576
__global__ __launch_bounds__(256, 2) void mlp_fused_k(
    const u16* __restrict__ xs,
    const u16* __restrict__ BT1, const float* __restrict__ b11,
    const u16* __restrict__ BT2, const float* __restrict__ b12,
    const u16* __restrict__ BT3, const float* __restrict__ b21,
    const u16* __restrict__ BT4, const float* __restrict__ b22,
    u16* __restrict__ Afin)
{
    __shared__ u16 lds[40960];     // 80 KB -> exactly 2 blocks/CU
    const int tid = threadIdx.x;
    const int row0 = blockIdx.x * 128;
    const int lane = tid & 63;
    const int wv = tid >> 6;
    const int wm = wv & 1, wn = wv >> 1;          // 2x2 wave grid
    const int quad = lane >> 4, cl = lane & 15;

    // prefetch thread mapping
    const int r1 = tid >> 2, s1 = tid & 3;        // W1 chunk: 64 rows x 16 segs
    const int r2 = tid >> 1, s2 = (tid & 1)*4;    // W2 chunk: 128 rows x 8 segs

    uintx4 w1r[4], w2r[4];
#pragma unroll
    for (int p = 0; p < 4; ++p){                  // prefetch chunk g=0
        w1r[p] = *(const uintx4*)(BT1 + (size_t)r1*128 + (s1 + 4*p)*8);
        w2r[p] = *(const uintx4*)(BT2 + (size_t)r2*512 + (s2 + p)*8);
    }
    {   // stage xs tile -> Abuf (swizzled)
        int rr = tid >> 4, seg = tid & 15;
        const u16* src = xs + (size_t)(row0 + rr)*128 + seg*8;
#pragma unroll
        for (int p = 0; p < 8; ++p)
            *(uintx4*)(lds + swz128(rr + p*16, seg)) = *(const uintx4*)(src + (size_t)p*16*128);
    }
    __syncthreads();

    for (int mlp = 0; mlp < 2; ++mlp){
        const float* ba = mlp ? b21 : b11;
        const float* bb = mlp ? b22 : b12;

        bf16x8 afrag[4][4];                       // A rows cached, reused all 8 chunks
#pragma unroll
        for (int mt = 0; mt < 4; ++mt)
#pragma unroll
            for (int ks = 0; ks < 4; ++ks)
                afrag[mt][ks] = *(const bf16x8*)(lds + swz128(wm*64 + mt*16 + cl, ks*4 + quad));

        if (mlp == 0){                            // store chunk0 (regions disjoint from Abuf)
#pragma unroll
            for (int p = 0; p < 4; ++p){
                *(uintx4*)(lds + W1B + swz128(r1, s1 + 4*p)) = w1r[p];
                *(uintx4*)(lds + W2B + swz64(r2, s2 + p))    = w2r[p];
            }
        }   // mlp==1: chunk8 already staged at end of mlp0/hc7

        floatx4 Yacc[16];
#pragma unroll
        for (int i = 0; i < 16; ++i) Yacc[i] = (floatx4){0.f,0.f,0.f,0.f};
        floatx4 hacc[8];

        for (int hc = 0; hc < 8; ++hc){
            const int g = mlp*8 + hc;
            __syncthreads();                      // S1: W[hc]/W2[hc&1]/Hbuf[(hc-1)&1] visible
            if (g < 15){                          // prefetch chunk g+1 (full iter to land)
                const u16* w1s = ((g+1) & 8) ? BT3 : BT1;
                const u16* w2s = ((g+1) & 8) ? BT4 : BT2;
                const int hb = ((g+1) & 7) * 64;
#pragma unroll
                for (int p = 0; p < 4; ++p){
                    w1r[p] = *(const uintx4*)(w1s + (size_t)(hb + r1)*128 + (s1 + 4*p)*8);
                    w2r[p] = *(const uintx4*)(w2s + (size_t)r2*512 + hb + (s2 + p)*8);
                }
            }
            // GEMM1[hc]: Hc = A x W1c   (128 x 64, K=128)
#pragma unroll
            for (int i = 0; i < 8; ++i) hacc[i] = (floatx4){0.f,0.f,0.f,0.f};
#pragma unroll
            for (int ks = 0; ks < 4; ++ks){
                bf16x8 b0 = *(const bf16x8*)(lds + W1B + swz128(wn*32 + cl,      ks*4 + quad));
                bf16x8 b1 = *(const bf16x8*)(lds + W1B + swz128(wn*32 + 16 + cl, ks*4 + quad));
#pragma unroll
                for (int mt = 0; mt < 4; ++mt){
                    hacc[mt*2+0] = MFMA16(afrag[mt][ks], b0, hacc[mt*2+0]);
                    hacc[mt*2+1] = MFMA16(afrag[mt][ks], b1, hacc[mt*2+1]);
                }
            }
            // GEMM2[hc-1]: Y += H[hc-1] x W2[hc-1]  (independent of hacc -> overlaps GELU)
            if (hc > 0){
                const int HBp = ((hc-1) & 1) * 8192;
                const int W2p = W2B + ((hc-1) & 1) * 8192;
#pragma unroll
                for (int ks = 0; ks < 2; ++ks){
                    bf16x8 a2[4], b2[4];
#pragma unroll
                    for (int mt = 0; mt < 4; ++mt) a2[mt] = *(const bf16x8*)(lds + HBp + swz64(wm*64 + mt*16 + cl, ks*4 + quad));
#pragma unroll
                    for (int nt = 0; nt < 4; ++nt) b2[nt] = *(const bf16x8*)(lds + W2p + swz64(wn*64 + nt*16 + cl, ks*4 + quad));
#pragma unroll
                    for (int mt = 0; mt < 4; ++mt)
#pragma unroll
                        for (int nt = 0; nt < 4; ++nt)
                            Yacc[mt*4+nt] = MFMA16(a2[mt], b2[nt], Yacc[mt*4+nt]);
                }
            }
            // GELU[hc] -> Hbuf[hc&1]
            {
                const int HB = (hc & 1) * 8192;
                int h0 = wn*32 + cl;
                int h1v = h0 + 16;
                float bav0 = ba[hc*64 + h0];
                float bav1 = ba[hc*64 + h1v];
#pragma unroll
                for (int mt = 0; mt < 4; ++mt){
                    floatx4 v0 = hacc[mt*2], v1 = hacc[mt*2+1];
#pragma unroll
                    for (int i = 0; i < 4; ++i){
                        int r = wm*64 + mt*16 + quad*4 + i;
                        lds[HB + r*64 + (((h0 >> 3) ^ r) & 7)*8 + (h0 & 7)]  = f2bf(fgelu(v0[i] + bav0));
                        lds[HB + r*64 + (((h1v >> 3) ^ r) & 7)*8 + (h1v & 7)] = f2bf(fgelu(v1[i] + bav1));
                    }
                }
            }
            __syncthreads();                      // S2: tiles consumed, GELU flushed
            if (g < 15){                          // stage chunk g+1 for next S1
#pragma unroll
                for (int p = 0; p < 4; ++p){
                    *(uintx4*)(lds + W1B + swz128(r1, s1 + 4*p))               = w1r[p];
                    *(uintx4*)(lds + W2B + ((hc+1)&1)*8192 + swz64(r2, s2 + p)) = w2r[p];
                }
            }
        }
        // drain: GEMM2[7]
        __syncthreads();                          // Hbuf[1] (GELU[7]) visible
        {
            const int HBp = 8192;
            const int W2p = W2B + 8192;
#pragma unroll
            for (int ks = 0; ks < 2; ++ks){
                bf16x8 a2[4], b2[4];
#pragma unroll
                for (int mt = 0; mt < 4; ++mt) a2[mt] = *(const bf16x8*)(lds + HBp + swz64(wm*64 + mt*16 + cl, ks*4 + quad));
#pragma unroll
                for (int nt = 0; nt < 4; ++nt) b2[nt] = *(const bf16x8*)(lds + W2p + swz64(wn*64 + nt*16 + cl, ks*4 + quad));
#pragma unroll
                for (int mt = 0; mt < 4; ++mt)
#pragma unroll
                    for (int nt = 0; nt < 4; ++nt)
                        Yacc[mt*4+nt] = MFMA16(a2[mt], b2[nt], Yacc[mt*4+nt]);
            }
        }
        __syncthreads();                          // all reads done

        if (mlp == 0){
            // h1 = Y + b12 -> bf16 -> Abuf (swizzled)
#pragma unroll
            for (int mt = 0; mt < 4; ++mt)
#pragma unroll
                for (int nt = 0; nt < 4; ++nt){
                    int c = wn*64 + nt*16 + cl;
                    float bv = bb[c];
                    floatx4 v = Yacc[mt*4+nt];
#pragma unroll
                    for (int i = 0; i < 4; ++i){
                        int r = wm*64 + mt*16 + quad*4 + i;
                        lds[r*128 + ((((c >> 3) & 8) | (((c >> 3) ^ r) & 7)) << 3) + (c & 7)] = f2bf(v[i] + bv);
                    }
                }
            __syncthreads();                      // h1 visible for mlp1 afrag
        } else {
            // h2 + b22 -> Afin[:, 512 + s*128 + n]  (row gr = bc*4+s)
#pragma unroll
            for (int mt = 0; mt < 4; ++mt)
#pragma unroll
                for (int nt = 0; nt < 4; ++nt){
                    int c = wn*64 + nt*16 + cl;
                    float bv = bb[c];
                    floatx4 v = Yacc[mt*4+nt];
#pragma unroll
                    for (int i = 0; i < 4; ++i){
                        int gr = row0 + wm*64 + mt*16 + quad*4 + i;
                        Afin[(size_t)(gr>>2)*1024 + 512 + (size_t)(gr&3)*128 + c] = f2bf(v[i] + bv);
                    }
                }
        }
    }
}

// ---------------- final fused-head GEMM: [41088][1024] x [384][1024]^T ----------------
__global__ __launch_bounds__(256, 3) void head_gemm_k(
    const u16* __restrict__ A, const u16* __restrict__ BT,
    float* __restrict__ Cf,
    const float* __restrict__ bias, const float* __restrict__ bias2,
    const float* __restrict__ rw, const float* __restrict__ rb,
    const float2* __restrict__ stats)
{
    __shared__ u16 lA[8192];
    __shared__ u16 lB[8192];
    const int tid = threadIdx.x;
    const int row0 = blockIdx.y * 128;
    const int col0 = blockIdx.x * 128;
    const int lane = tid & 63;
    const int wv = tid >> 6;
    const int wm = wv & 1, wn = wv >> 1;
    const int quad = lane >> 4, cl = lane & 15;

    floatx4 acc[16];
#pragma unroll
    for (int i = 0; i < 16; ++i) acc[i] = (floatx4){0.f,0.f,0.f,0.f};

    const int rs = tid >> 1, ss = (tid & 1)*4;    // 128 rows x 8 segs per tile
    const u16* Ag = A  + (size_t)(row0 + rs)*1024 + ss*8;
    const u16* Bg = BT + (size_t)(col0 + rs)*1024 + ss*8;

    uintx4 arA[4], arB[4];
#pragma unroll
    for (int p = 0; p < 4; ++p){                  // prefetch k-slice 0
        arA[p] = *(const uintx4*)(Ag + p*8);
        arB[p] = *(const uintx4*)(Bg + p*8);
    }

    for (int it = 0; it < 16; ++it){
#pragma unroll
        for (int p = 0; p < 4; ++p){              // regs -> LDS (swizzled)
            *(uintx4*)(lA + swz64(rs, ss + p)) = arA[p];
            *(uintx4*)(lB + swz64(rs, ss + p)) = arB[p];
        }
        __syncthreads();
        if (it < 15){                             // prefetch next slice during MFMA
#pragma unroll
            for (int p = 0; p < 4; ++p){
                arA[p] = *(const uintx4*)(Ag + (it+1)*64 + p*8);
                arB[p] = *(const uintx4*)(Bg + (it+1)*64 + p*8);
            }
        }
#pragma unroll
        for (int kk = 0; kk < 2; ++kk){
            bf16x8 af[4], bfr[4];
#pragma unroll
            for (int mt = 0; mt < 4; ++mt) af[mt]  = *(const bf16x8*)(lA + swz64(wm*64 + mt*16 + cl, kk*4 + quad));
#pragma unroll
            for (int nt = 0; nt < 4; ++nt) bfr[nt] = *(const bf16x8*)(lB + swz64(wn*64 + nt*16 + cl, kk*4 + quad));
#pragma unroll
            for (int mt = 0; mt < 4; ++mt)
#pragma unroll
                for (int nt = 0; nt < 4; ++nt)
                    acc[mt*4+nt] = MFMA16(af[mt], bfr[nt], acc[mt*4+nt]);
        }
        __syncthreads();
    }

#pragma unroll
    for (int mt = 0; mt < 4; ++mt)
#pragma unroll
        for (int nt = 0; nt < 4; ++nt){
            floatx4 v = acc[mt*4+nt];
            int gc = col0 + wn*64 + nt*16 + cl;
            if (gc >= PREDD) continue;
            float bsum = bias[gc] + bias2[gc];
#pragma unroll
            for (int i = 0; i < 4; ++i){
                int gr = row0 + wm*64 + mt*16 + quad*4 + i;
                float val = v[i] + bsum;
                int bv2 = gr / CC;
                int c  = gr - bv2*CC;
                val = (val - rb[c]) / (rw[c] + 1e-10f);
                float2 st = stats[gr];
                val = val*st.y + st.x;
                Cf[(size_t)bv2*(PREDD*CC) + (size_t)gc*CC + c] = val;
            }
        }
}

extern "C" void kernel_launch(void* const* d_in, const int* in_sizes, int n_in,
                              void* d_out, int out_size, void* d_ws, size_t ws_size,
                              hipStream_t stream)
{
    const float* x   = (const float*)d_in[0];
    const float* rvw = (const float*)d_in[1];
    const float* rvb = (const float*)d_in[2];
    const float* W11 = (const float*)d_in[3];
    const float* b11 = (const float*)d_in[4];
    const float* W12 = (const float*)d_in[5];
    const float* b12 = (const float*)d_in[6];
    const float* W21 = (const float*)d_in[7];
    const float* b21 = (const float*)d_in[8];
    const float* W22 = (const float*)d_in[9];
    const float* b22 = (const float*)d_in[10];
    const float* Wtr = (const float*)d_in[11];
    const float* btr = (const float*)d_in[12];
    const float* Wse = (const float*)d_in[13];
    const float* bse = (const float*)d_in[14];
    float* out = (float*)d_out;

    char* ws = (char*)d_ws;
    u16* BT1 = (u16*)(ws + 0);            //  512x128 bf16
    u16* BT2 = (u16*)(ws + 131072);       //  128x512
    u16* BT3 = (u16*)(ws + 262144);       //  512x128
    u16* BT4 = (u16*)(ws + 393216);       //  128x512
    u16* BT5 = (u16*)(ws + 524288);       //  384x1024
    float2* stats = (float2*)(ws + 1310720);      // 41088 x {mean,std}
    u16* Afin = (u16*)(ws + 1639424);     // concat-A [41088][1024]: trend | sea
    u16* xs   = (u16*)(ws + 85787648);    // [164352][128] split seasonal

    hipLaunchKernelGGL(prep_k, dim3(1536), dim3(256), 0, stream,
                       W11, W12, W21, W22, Wtr, Wse, BT1, BT2, BT3, BT4, BT5);
    hipLaunchKernelGGL(decomp_k, dim3(128*21), dim3(256), 0, stream,
                       x, rvw, rvb, Afin, xs, stats);
    hipLaunchKernelGGL(mlp_fused_k, dim3(1284), dim3(256), 0, stream,
                       xs, BT1, b11, BT2, b12, BT3, b21, BT4, b22, Afin);
    hipLaunchKernelGGL(head_gemm_k, dim3(3, 321), dim3(256), 0, stream,
                       Afin, BT5, out, btr, bse, rvw, rvb, stats);
}

// Round 6
// 513.988 us; speedup vs baseline: 1.3082x; 1.3082x over previous
//
#include <hip/hip_runtime.h>
#include <math.h>

// Problem constants
#define BB   128
#define LL   512
#define CC   321
#define PREDD 336
// Seasonal MLP: rows = B*C*S = 164352, dims 128 -> 512 -> 128 (x2 blocks)

using bf16x8  = __attribute__((ext_vector_type(8))) __bf16;
using floatx4 = __attribute__((ext_vector_type(4))) float;
using uintx4  = __attribute__((ext_vector_type(4))) unsigned int;
typedef unsigned short u16;
typedef unsigned int u32;

#define MFMA16(a,b,c) __builtin_amdgcn_mfma_f32_16x16x32_bf16(a,b,c,0,0,0)

__device__ __forceinline__ u16 f2bf(float f){
    union { float f; unsigned u; } v; v.f = f;
    unsigned r = v.u + 0x7FFFu + ((v.u >> 16) & 1u);   // RNE
    return (u16)(r >> 16);
}

// tanh-GELU via exp2: max |err| vs exact erf-GELU ~3e-4 << bf16 rounding.
__device__ __forceinline__ float fgelu(float x){
    float u = x*(0.7978845608f + 0.035677408f*x*x);
    float a = fminf(u*2.8853900818f, 80.f);       // 2*log2(e)*u, clamp vs inf/inf
    float t = __builtin_amdgcn_exp2f(a);          // v_exp_f32
    return x*t*__builtin_amdgcn_rcpf(1.f + t);
}

// XOR-segment swizzle (16B segs): s' = (s&8)|((s^r)&7) -- self-inverse.
__device__ __forceinline__ int swz128(int r, int s){ return r*128 + (((s & 8) | ((s ^ r) & 7)) << 3); }
__device__ __forceinline__ int swz64 (int r, int s){ return r*64  + (((s ^ r) & 7) << 3); }

// async global->LDS DMA, 16B per lane; LDS dest = uniform base + lane*16.
// Global address is per-lane arbitrary -> swizzle is applied on the GLOBAL side.
__device__ __forceinline__ void dma16(const u16* g, const u16* l){
    __builtin_amdgcn_global_load_lds(
        (const __attribute__((address_space(1))) u32*)g,
        (__attribute__((address_space(3))) u32*)l, 16, 0, 0);
}

// ---------------- weight prep: fp32 -> bf16, pre-transposed [Ncols][K] ----------------
__global__ void prep_k(const float* __restrict__ W11, const float* __restrict__ W12,
                       const float* __restrict__ W21, const float* __restrict__ W22,
                       const float* __restrict__ Wtr, const float* __restrict__ Wse,
                       u16* __restrict__ BT1, u16* __restrict__ BT2,
                       u16* __restrict__ BT3, u16* __restrict__ BT4,
                       u16* __restrict__ BT5)
{
    int idx = blockIdx.x * 256 + threadIdx.x;
    if (idx < 65536){
        int h = idx >> 7, k = idx & 127;          // BT1/BT3: [512][128] = W11^T / W21^T
        BT1[idx] = f2bf(W11[k*512 + h]);
        BT3[idx] = f2bf(W21[k*512 + h]);
        int n = idx >> 9, k2 = idx & 511;         // BT2/BT4: [128][512] = W12^T / W22^T
        BT2[idx] = f2bf(W12[k2*128 + n]);
        BT4[idx] = f2bf(W22[k2*128 + n]);
    }
    if (idx < 393216){
        // BT5: [384][1024]; k<512 -> W_tr rows; k>=512 -> W_se rows permuted to (s,n)-major
        int p = idx >> 10, k = idx & 1023;
        float v = 0.f;
        if (p < PREDD){
            if (k < 512) v = Wtr[k*PREDD + p];
            else { int kk = k - 512; int s = kk >> 7; int n = kk & 127; v = Wse[(4*n + s)*PREDD + p]; }
        }
        BT5[idx] = f2bf(v);
    }
}

// ---------------- fused RevIN stats + moving-avg decomposition ----------------
#define XT(t,c) xt[((t)<<4) + (((t)>>5)<<1) + (c)]
__global__ __launch_bounds__(256) void decomp_k(
    const float* __restrict__ x, const float* __restrict__ rw, const float* __restrict__ rb,
    u16* __restrict__ Afin, u16* __restrict__ xs, float2* __restrict__ stats)
{
    __shared__ float xt[8240];
    __shared__ float red[2][16][16];
    __shared__ float sh_m[16], sh_istd[16];
    int b = blockIdx.x / 21, ct = blockIdx.x % 21;
    int tid = threadIdx.x;

    int cl = tid & 15, lp = tid >> 4;
    int c = ct*16 + cl;
    bool valid = c < CC;
    const float* xb = x + (size_t)b*LL*CC;
    float s = 0.f, q = 0.f;
    for (int i = 0; i < 32; ++i){
        int t = lp + 16*i;
        float v = valid ? xb[(size_t)t*CC + c] : 0.f;
        XT(t, cl) = v;
        s += v; q += v*v;
    }
    red[0][lp][cl] = s; red[1][lp][cl] = q;
    __syncthreads();
    if (tid < 16){
        float ss = 0.f, qq = 0.f;
        for (int j = 0; j < 16; ++j){ ss += red[0][j][tid]; qq += red[1][j][tid]; }
        float m  = ss * (1.f/512.f);
        float var = qq * (1.f/512.f) - m*m;
        float sd = sqrtf(var + 1e-5f);
        sh_m[tid] = m; sh_istd[tid] = 1.f/sd;
        int cc = ct*16 + tid;
        if (cc < CC) stats[(size_t)b*CC + cc] = make_float2(m, sd);
    }
    __syncthreads();

    int ch = tid >> 4, tp = tid & 15;
    int c2 = ct*16 + ch;
    if (c2 >= CC) return;
    float m = sh_m[ch], istd = sh_istd[ch];
    float w = rw[c2] * istd, bbv = rb[c2];
    size_t bc = (size_t)b*CC + c2;
    u16* tr  = Afin + bc*1024;
    u16* xsr = xs   + bc*512;
    int t0 = tp*32;

    float win = 0.f;
#pragma unroll
    for (int d = -12; d <= 12; ++d){
        int u = t0 + d; u = u < 0 ? 0 : (u > 511 ? 511 : u);
        win += XT(u, ch);
    }
    u16 trbuf[8];
    u16 xsbuf[4][8];
#pragma unroll
    for (int i = 0; i < 32; ++i){
        int t = t0 + i;
        float Ax = win * (1.f/25.f);
        float xv = XT(t, ch);
        trbuf[i & 7] = f2bf((Ax - m)*w + bbv);
        xsbuf[i & 3][i >> 2] = f2bf((xv - Ax)*w);
        if ((i & 7) == 7)
            *(uintx4*)(tr + t0 + (i & ~7)) = *(const uintx4*)trbuf;
        int uo = t - 12; uo = uo < 0 ? 0 : uo;
        int un = t + 13; un = un > 511 ? 511 : un;
        win += XT(un, ch) - XT(uo, ch);
    }
#pragma unroll
    for (int s4 = 0; s4 < 4; ++s4)
        *(uintx4*)(xsr + s4*128 + tp*8) = *(const uintx4*)xsbuf[s4];
}

// ---------------- fully fused 2-block MLP, DMA-pipelined, 64 KB LDS ----------------
// LDS (u16): W1buf [0,8192) 64x128 swz128 ; Hbuf [8192,16384) 128x64 swz64 ;
//            W2 slots [16384,24576),[24576,32768) 128x64 swz64.
// xs tile staged initially at [16384,32768); h1 tile at [0,16384) at transition.
// Per iter: S1 -> GEMM1 (W1[g]) -> GELU -> S2 -> DMA W1[g+1],W2[g+1] -> GEMM2 (W2[g]) -> loop.
#define RW1 0
#define RH  8192
#define RW2 16384
__global__ __launch_bounds__(256, 2) void mlp_fused_k(
    const u16* __restrict__ xs,
    const u16* __restrict__ BT1, const float* __restrict__ b11,
    const u16* __restrict__ BT2, const float* __restrict__ b12,
    const u16* __restrict__ BT3, const float* __restrict__ b21,
    const u16* __restrict__ BT4, const float* __restrict__ b22,
    u16* __restrict__ Afin)
{
    __shared__ u16 lds[32768];     // 64 KB -> 2 blocks/CU
    const int tid = threadIdx.x;
    const int row0 = blockIdx.x * 128;
    const int lane = tid & 63;
    const int wv = tid >> 6;
    const int wm = wv & 1, wn = wv >> 1;          // 2x2 wave grid
    const int quad = lane >> 4, cl = lane & 15;

    // ---- stage xs tile (32 KB) -> [RW2, +16384) as swz128 image, via DMA
#pragma unroll
    for (int i = 0; i < 8; ++i){
        int qq = (wv*8 + i)*64 + lane;
        int r = qq >> 4, sp = qq & 15;
        int s = (sp & 8) | ((sp ^ r) & 7);
        dma16(xs + (size_t)(row0 + r)*128 + s*8, lds + RW2 + qq*8);
    }
    __syncthreads();

    bf16x8 afrag[4][4];
#pragma unroll
    for (int mt = 0; mt < 4; ++mt)
#pragma unroll
        for (int ks = 0; ks < 4; ++ks)
            afrag[mt][ks] = *(const bf16x8*)(lds + RW2 + swz128(wm*64 + mt*16 + cl, ks*4 + quad));
    __syncthreads();                              // xs reads done before W2[0] overwrite

    // DMA chunk 0: W1[0] -> RW1 (swz128 image), W2[0] -> slot0 (swz64 image)
#pragma unroll
    for (int i = 0; i < 4; ++i){
        int qq = (wv*4 + i)*64 + lane;
        { int r = qq >> 4, sp = qq & 15; int s = (sp & 8) | ((sp ^ r) & 7);
          dma16(BT1 + (size_t)r*128 + s*8, lds + RW1 + qq*8); }
        { int r = qq >> 3, p = qq & 7; int s = (p ^ r) & 7;
          dma16(BT2 + (size_t)r*512 + s*8, lds + RW2 + qq*8); }
    }
    __syncthreads();                              // chunk 0 landed

    for (int mlp = 0; mlp < 2; ++mlp){
        const float* ba = mlp ? b21 : b11;
        const float* bb = mlp ? b22 : b12;

        floatx4 Yacc[16];
#pragma unroll
        for (int i = 0; i < 16; ++i) Yacc[i] = (floatx4){0.f,0.f,0.f,0.f};

        for (int hc = 0; hc < 8; ++hc){
            const int g = mlp*8 + hc;
            // GEMM1[g]: hacc = afrag x W1frag  (128x64, K=128)
            floatx4 hacc[8];
#pragma unroll
            for (int i = 0; i < 8; ++i) hacc[i] = (floatx4){0.f,0.f,0.f,0.f};
#pragma unroll
            for (int ks = 0; ks < 4; ++ks){
                bf16x8 b0 = *(const bf16x8*)(lds + RW1 + swz128(wn*32 + cl,      ks*4 + quad));
                bf16x8 b1 = *(const bf16x8*)(lds + RW1 + swz128(wn*32 + 16 + cl, ks*4 + quad));
#pragma unroll
                for (int mt = 0; mt < 4; ++mt){
                    hacc[mt*2+0] = MFMA16(afrag[mt][ks], b0, hacc[mt*2+0]);
                    hacc[mt*2+1] = MFMA16(afrag[mt][ks], b1, hacc[mt*2+1]);
                }
            }
            // GELU[g] -> Hbuf (swz64)
            {
                int h0 = wn*32 + cl, h1v = h0 + 16;
                float bav0 = ba[hc*64 + h0];
                float bav1 = ba[hc*64 + h1v];
#pragma unroll
                for (int mt = 0; mt < 4; ++mt){
                    floatx4 v0 = hacc[mt*2], v1 = hacc[mt*2+1];
#pragma unroll
                    for (int i = 0; i < 4; ++i){
                        int r = wm*64 + mt*16 + quad*4 + i;
                        lds[RH + r*64 + (((h0 >> 3) ^ r) & 7)*8 + (h0 & 7)]   = f2bf(fgelu(v0[i] + bav0));
                        lds[RH + r*64 + (((h1v >> 3) ^ r) & 7)*8 + (h1v & 7)] = f2bf(fgelu(v1[i] + bav1));
                    }
                }
            }
            __syncthreads();                      // S2: W1[g]/Hbuf consumers+producers synced
            // DMA chunk g+1 (flies over GEMM2); W1 delayed at mlp transition (hc==7)
            if (g < 15){
                const u16* w1s = ((g+1) & 8) ? BT3 : BT1;
                const u16* w2s = ((g+1) & 8) ? BT4 : BT2;
                const int hb = ((g+1) & 7) * 64;
                const int slot = RW2 + ((hc+1) & 1) * 8192;
#pragma unroll
                for (int i = 0; i < 4; ++i){
                    int qq = (wv*4 + i)*64 + lane;
                    if (hc < 7){
                        int r = qq >> 4, sp = qq & 15; int s = (sp & 8) | ((sp ^ r) & 7);
                        dma16(w1s + (size_t)(hb + r)*128 + s*8, lds + RW1 + qq*8);
                    }
                    int r2 = qq >> 3, p2 = qq & 7; int s2 = (p2 ^ r2) & 7;
                    dma16(w2s + (size_t)r2*512 + hb + s2*8, lds + slot + qq*8);
                }
            }
            // GEMM2[g]: Yacc += Hfrag x W2frag (slot hc&1), K=64
            {
                const int W2p = RW2 + (hc & 1) * 8192;
#pragma unroll
                for (int ks = 0; ks < 2; ++ks){
                    bf16x8 a2[4], b2[4];
#pragma unroll
                    for (int mt = 0; mt < 4; ++mt) a2[mt] = *(const bf16x8*)(lds + RH  + swz64(wm*64 + mt*16 + cl, ks*4 + quad));
#pragma unroll
                    for (int nt = 0; nt < 4; ++nt) b2[nt] = *(const bf16x8*)(lds + W2p + swz64(wn*64 + nt*16 + cl, ks*4 + quad));
#pragma unroll
                    for (int mt = 0; mt < 4; ++mt)
#pragma unroll
                        for (int nt = 0; nt < 4; ++nt)
                            Yacc[mt*4+nt] = MFMA16(a2[mt], b2[nt], Yacc[mt*4+nt]);
                }
            }
            __syncthreads();                      // S1: reads done + DMA drained (vmcnt)
        }

        if (mlp == 0){
            // h1 = Y + b12 -> bf16 -> [0,16384) swz128 image
#pragma unroll
            for (int mt = 0; mt < 4; ++mt)
#pragma unroll
                for (int nt = 0; nt < 4; ++nt){
                    int c = wn*64 + nt*16 + cl;
                    float bv = bb[c];
                    floatx4 v = Yacc[mt*4+nt];
#pragma unroll
                    for (int i = 0; i < 4; ++i){
                        int r = wm*64 + mt*16 + quad*4 + i;
                        lds[swz128(r, c >> 3) + (c & 7)] = f2bf(v[i] + bv);
                    }
                }
            __syncthreads();                      // h1 complete
#pragma unroll
            for (int mt = 0; mt < 4; ++mt)
#pragma unroll
                for (int ks = 0; ks < 4; ++ks)
                    afrag[mt][ks] = *(const bf16x8*)(lds + swz128(wm*64 + mt*16 + cl, ks*4 + quad));
            __syncthreads();                      // h1 reads done before W1[8] overwrite
            // DMA W1[8] -> RW1 (W2[8] already in slot0 from g=7)
#pragma unroll
            for (int i = 0; i < 4; ++i){
                int qq = (wv*4 + i)*64 + lane;
                int r = qq >> 4, sp = qq & 15; int s = (sp & 8) | ((sp ^ r) & 7);
                dma16(BT3 + (size_t)r*128 + s*8, lds + RW1 + qq*8);
            }
            __syncthreads();                      // W1[8] landed
        } else {
            // h2 + b22 -> Afin[:, 512 + s*128 + n]  (row gr = bc*4+s)
#pragma unroll
            for (int mt = 0; mt < 4; ++mt)
#pragma unroll
                for (int nt = 0; nt < 4; ++nt){
                    int c = wn*64 + nt*16 + cl;
                    float bv = bb[c];
                    floatx4 v = Yacc[mt*4+nt];
#pragma unroll
                    for (int i = 0; i < 4; ++i){
                        int gr = row0 + wm*64 + mt*16 + quad*4 + i;
                        Afin[(size_t)(gr>>2)*1024 + 512 + (size_t)(gr&3)*128 + c] = f2bf(v[i] + bv);
                    }
                }
        }
    }
}

// ---------------- final fused-head GEMM, DMA double-buffered, XCD-grouped ----------------
// grid 984 (21 dead). Siblings j=0..2 of a row-group share id%8 -> same XCD -> A-tile L2 reuse.
__global__ __launch_bounds__(256, 2) void head_gemm_k(
    const u16* __restrict__ A, const u16* __restrict__ BT,
    float* __restrict__ Cf,
    const float* __restrict__ bias, const float* __restrict__ bias2,
    const float* __restrict__ rw, const float* __restrict__ rb,
    const float2* __restrict__ stats)
{
    __shared__ u16 lds[32768];    // A slices @0,@8192 ; B slices @16384,@24576
    const int id = blockIdx.x;
    const int xcd = id & 7, slot = id >> 3;
    const int g8 = slot / 3, j = slot - g8*3;
    const int by = xcd + 8*g8;
    if (by >= 321) return;
    const int row0 = by * 128, col0 = j * 128;

    const int tid = threadIdx.x;
    const int lane = tid & 63;
    const int wv = tid >> 6;
    const int wm = wv & 1, wn = wv >> 1;
    const int quad = lane >> 4, cl = lane & 15;

    // per-lane DMA coords for [128][64] swz64 slice images
    const int qbase = wv*4*64 + lane;

    // prologue: slice 0 -> buffers 0
#pragma unroll
    for (int i = 0; i < 4; ++i){
        int qq = qbase + i*64;
        int r = qq >> 3, p = qq & 7; int s = (p ^ r) & 7;
        dma16(A  + (size_t)(row0 + r)*1024 + s*8, lds + qq*8);
        dma16(BT + (size_t)(col0 + r)*1024 + s*8, lds + 16384 + qq*8);
    }
    __syncthreads();

    floatx4 acc[16];
#pragma unroll
    for (int i = 0; i < 16; ++i) acc[i] = (floatx4){0.f,0.f,0.f,0.f};

    for (int it = 0; it < 16; ++it){
        const int cur = (it & 1) * 8192;
        if (it < 15){                             // DMA next slice into other buffers
            const int nxt = ((it+1) & 1) * 8192;
            const int k0 = (it+1) * 64;
#pragma unroll
            for (int i = 0; i < 4; ++i){
                int qq = qbase + i*64;
                int r = qq >> 3, p = qq & 7; int s = (p ^ r) & 7;
                dma16(A  + (size_t)(row0 + r)*1024 + k0 + s*8, lds + nxt + qq*8);
                dma16(BT + (size_t)(col0 + r)*1024 + k0 + s*8, lds + 16384 + nxt + qq*8);
            }
        }
#pragma unroll
        for (int kk = 0; kk < 2; ++kk){
            bf16x8 af[4], bfr[4];
#pragma unroll
            for (int mt = 0; mt < 4; ++mt) af[mt]  = *(const bf16x8*)(lds + cur + swz64(wm*64 + mt*16 + cl, kk*4 + quad));
#pragma unroll
            for (int nt = 0; nt < 4; ++nt) bfr[nt] = *(const bf16x8*)(lds + 16384 + cur + swz64(wn*64 + nt*16 + cl, kk*4 + quad));
#pragma unroll
            for (int mt = 0; mt < 4; ++mt)
#pragma unroll
                for (int nt = 0; nt < 4; ++nt)
                    acc[mt*4+nt] = MFMA16(af[mt], bfr[nt], acc[mt*4+nt]);
        }
        __syncthreads();                          // reads done + next DMA drained
    }

#pragma unroll
    for (int mt = 0; mt < 4; ++mt)
#pragma unroll
        for (int nt = 0; nt < 4; ++nt){
            floatx4 v = acc[mt*4+nt];
            int gc = col0 + wn*64 + nt*16 + cl;
            if (gc >= PREDD) continue;
            float bsum = bias[gc] + bias2[gc];
#pragma unroll
            for (int i = 0; i < 4; ++i){
                int gr = row0 + wm*64 + mt*16 + quad*4 + i;
                float val = v[i] + bsum;
                int bv2 = gr / CC;
                int c  = gr - bv2*CC;
                val = (val - rb[c]) / (rw[c] + 1e-10f);
                float2 st = stats[gr];
                val = val*st.y + st.x;
                Cf[(size_t)bv2*(PREDD*CC) + (size_t)gc*CC + c] = val;
            }
        }
}

extern "C" void kernel_launch(void* const* d_in, const int* in_sizes, int n_in,
                              void* d_out, int out_size, void* d_ws, size_t ws_size,
                              hipStream_t stream)
{
    const float* x   = (const float*)d_in[0];
    const float* rvw = (const float*)d_in[1];
    const float* rvb = (const float*)d_in[2];
    const float* W11 = (const float*)d_in[3];
    const float* b11 = (const float*)d_in[4];
    const float* W12 = (const float*)d_in[5];
    const float* b12 = (const float*)d_in[6];
    const float* W21 = (const float*)d_in[7];
    const float* b21 = (const float*)d_in[8];
    const float* W22 = (const float*)d_in[9];
    const float* b22 = (const float*)d_in[10];
    const float* Wtr = (const float*)d_in[11];
    const float* btr = (const float*)d_in[12];
    const float* Wse = (const float*)d_in[13];
    const float* bse = (const float*)d_in[14];
    float* out = (float*)d_out;

    char* ws = (char*)d_ws;
    u16* BT1 = (u16*)(ws + 0);            //  512x128 bf16
    u16* BT2 = (u16*)(ws + 131072);       //  128x512
    u16* BT3 = (u16*)(ws + 262144);       //  512x128
    u16* BT4 = (u16*)(ws + 393216);       //  128x512
    u16* BT5 = (u16*)(ws + 524288);       //  384x1024
    float2* stats = (float2*)(ws + 1310720);      // 41088 x {mean,std}
    u16* Afin = (u16*)(ws + 1639424);     // concat-A [41088][1024]: trend | sea
    u16* xs   = (u16*)(ws + 85787648);    // [164352][128] split seasonal

    hipLaunchKernelGGL(prep_k, dim3(1536), dim3(256), 0, stream,
                       W11, W12, W21, W22, Wtr, Wse, BT1, BT2, BT3, BT4, BT5);
    hipLaunchKernelGGL(decomp_k, dim3(128*21), dim3(256), 0, stream,
                       x, rvw, rvb, Afin, xs, stats);
    hipLaunchKernelGGL(mlp_fused_k, dim3(1284), dim3(256), 0, stream,
                       xs, BT1, b11, BT2, b12, BT3, b21, BT4, b22, Afin);
    hipLaunchKernelGGL(head_gemm_k, dim3(984), dim3(256), 0, stream,
                       Afin, BT5, out, btr, bse, rvw, rvb, stats);
}

// Round 7
// 451.166 us; speedup vs baseline: 1.4903x; 1.1392x over previous
//
#include <hip/hip_runtime.h>
#include <math.h>

// Problem constants
#define BB   128
#define LL   512
#define CC   321
#define PREDD 336
// Seasonal MLP: rows = B*C*S = 164352, dims 128 -> 512 -> 128 (x2 blocks)

using bf16x8  = __attribute__((ext_vector_type(8))) __bf16;
using floatx4 = __attribute__((ext_vector_type(4))) float;
using uintx4  = __attribute__((ext_vector_type(4))) unsigned int;
typedef unsigned short u16;
typedef unsigned int u32;

#define MFMA16(a,b,c) __builtin_amdgcn_mfma_f32_16x16x32_bf16(a,b,c,0,0,0)

__device__ __forceinline__ u16 f2bf(float f){
    union { float f; unsigned u; } v; v.f = f;
    unsigned r = v.u + 0x7FFFu + ((v.u >> 16) & 1u);   // RNE
    return (u16)(r >> 16);
}

// tanh-GELU via exp2: max |err| vs exact erf-GELU ~3e-4 << bf16 rounding.
__device__ __forceinline__ float fgelu(float x){
    float u = x*(0.7978845608f + 0.035677408f*x*x);
    float a = fminf(u*2.8853900818f, 80.f);       // 2*log2(e)*u, clamp vs inf/inf
    float t = __builtin_amdgcn_exp2f(a);          // v_exp_f32
    return x*t*__builtin_amdgcn_rcpf(1.f + t);
}

// XOR-segment swizzle (16B segs): s' = (s&8)|((s^r)&7) -- self-inverse.
__device__ __forceinline__ int swz128(int r, int s){ return r*128 + (((s & 8) | ((s ^ r) & 7)) << 3); }
__device__ __forceinline__ int swz64 (int r, int s){ return r*64  + (((s ^ r) & 7) << 3); }

// async global->LDS DMA, 16B per lane; LDS dest = uniform base + lane*16.
__device__ __forceinline__ void dma16(const u16* g, const u16* l){
    __builtin_amdgcn_global_load_lds(
        (const __attribute__((address_space(1))) u32*)g,
        (__attribute__((address_space(3))) u32*)l, 16, 0, 0);
}

// ---------------- weight prep: fp32 -> bf16, pre-transposed [Ncols][K] ----------------
__global__ void prep_k(const float* __restrict__ W11, const float* __restrict__ W12,
                       const float* __restrict__ W21, const float* __restrict__ W22,
                       const float* __restrict__ Wtr, const float* __restrict__ Wse,
                       u16* __restrict__ BT1, u16* __restrict__ BT2,
                       u16* __restrict__ BT3, u16* __restrict__ BT4,
                       u16* __restrict__ BT5)
{
    int idx = blockIdx.x * 256 + threadIdx.x;
    if (idx < 65536){
        int h = idx >> 7, k = idx & 127;          // BT1/BT3: [512][128] = W11^T / W21^T
        BT1[idx] = f2bf(W11[k*512 + h]);
        BT3[idx] = f2bf(W21[k*512 + h]);
        int n = idx >> 9, k2 = idx & 511;         // BT2/BT4: [128][512] = W12^T / W22^T
        BT2[idx] = f2bf(W12[k2*128 + n]);
        BT4[idx] = f2bf(W22[k2*128 + n]);
    }
    if (idx < 393216){
        // BT5: [384][1024]; k<512 -> W_tr rows; k>=512 -> W_se rows permuted to (s,n)-major
        int p = idx >> 10, k = idx & 1023;
        float v = 0.f;
        if (p < PREDD){
            if (k < 512) v = Wtr[k*PREDD + p];
            else { int kk = k - 512; int s = kk >> 7; int n = kk & 127; v = Wse[(4*n + s)*PREDD + p]; }
        }
        BT5[idx] = f2bf(v);
    }
}

// ---------------- fused RevIN stats + moving-avg decomposition ----------------
#define XT(t,c) xt[((t)<<4) + (((t)>>5)<<1) + (c)]
__global__ __launch_bounds__(256) void decomp_k(
    const float* __restrict__ x, const float* __restrict__ rw, const float* __restrict__ rb,
    u16* __restrict__ Afin, u16* __restrict__ xs, float2* __restrict__ stats)
{
    __shared__ float xt[8240];
    __shared__ float red[2][16][16];
    __shared__ float sh_m[16], sh_istd[16];
    int b = blockIdx.x / 21, ct = blockIdx.x % 21;
    int tid = threadIdx.x;

    int cl = tid & 15, lp = tid >> 4;
    int c = ct*16 + cl;
    bool valid = c < CC;
    const float* xb = x + (size_t)b*LL*CC;
    float s = 0.f, q = 0.f;
    for (int i = 0; i < 32; ++i){
        int t = lp + 16*i;
        float v = valid ? xb[(size_t)t*CC + c] : 0.f;
        XT(t, cl) = v;
        s += v; q += v*v;
    }
    red[0][lp][cl] = s; red[1][lp][cl] = q;
    __syncthreads();
    if (tid < 16){
        float ss = 0.f, qq = 0.f;
        for (int j = 0; j < 16; ++j){ ss += red[0][j][tid]; qq += red[1][j][tid]; }
        float m  = ss * (1.f/512.f);
        float var = qq * (1.f/512.f) - m*m;
        float sd = sqrtf(var + 1e-5f);
        sh_m[tid] = m; sh_istd[tid] = 1.f/sd;
        int cc = ct*16 + tid;
        if (cc < CC) stats[(size_t)b*CC + cc] = make_float2(m, sd);
    }
    __syncthreads();

    int ch = tid >> 4, tp = tid & 15;
    int c2 = ct*16 + ch;
    if (c2 >= CC) return;
    float m = sh_m[ch], istd = sh_istd[ch];
    float w = rw[c2] * istd, bbv = rb[c2];
    size_t bc = (size_t)b*CC + c2;
    u16* tr  = Afin + bc*1024;
    u16* xsr = xs   + bc*512;
    int t0 = tp*32;

    float win = 0.f;
#pragma unroll
    for (int d = -12; d <= 12; ++d){
        int u = t0 + d; u = u < 0 ? 0 : (u > 511 ? 511 : u);
        win += XT(u, ch);
    }
    u16 trbuf[8];
    u16 xsbuf[4][8];
#pragma unroll
    for (int i = 0; i < 32; ++i){
        int t = t0 + i;
        float Ax = win * (1.f/25.f);
        float xv = XT(t, ch);
        trbuf[i & 7] = f2bf((Ax - m)*w + bbv);
        xsbuf[i & 3][i >> 2] = f2bf((xv - Ax)*w);
        if ((i & 7) == 7)
            *(uintx4*)(tr + t0 + (i & ~7)) = *(const uintx4*)trbuf;
        int uo = t - 12; uo = uo < 0 ? 0 : uo;
        int un = t + 13; un = un > 511 ? 511 : un;
        win += XT(un, ch) - XT(uo, ch);
    }
#pragma unroll
    for (int s4 = 0; s4 < 4; ++s4)
        *(uintx4*)(xsr + s4*128 + tp*8) = *(const uintx4*)xsbuf[s4];
}

// ---------------- fused 2-block MLP, wave-independent rows ----------------
// Each wave owns 32 rows end-to-end. Block-wide coupling ONLY for weight
// staging (DMA double-buffered slots, ONE barrier per chunk). GELU'd H and
// the h1 handoff go through a private 4KB per-wave LDS scratch (no barriers).
// LDS (u16): slot0 [0,16384) = W1c[64x128]swz128 @0 + W2c[128x64]swz64 @8192
//            slot1 [16384,32768) same ; Hscr [32768,40960) = 4 waves x 2048.
// Scratch layout: (r,h) -> r*64 + (h ^ (((r>>2)&3)<<4))  (2-way max, b128-clean)
#define SL1 16384
#define HS  32768
__global__ __launch_bounds__(256, 2) void mlp_fused_k(
    const u16* __restrict__ xs,
    const u16* __restrict__ BT1, const float* __restrict__ b11,
    const u16* __restrict__ BT2, const float* __restrict__ b12,
    const u16* __restrict__ BT3, const float* __restrict__ b21,
    const u16* __restrict__ BT4, const float* __restrict__ b22,
    u16* __restrict__ Afin)
{
    __shared__ u16 lds[40960];     // 80 KB -> 2 blocks/CU
    const int tid = threadIdx.x;
    const int row0 = blockIdx.x * 128;
    const int lane = tid & 63;
    const int wv = tid >> 6;
    const int quad = lane >> 4, cl = lane & 15;
    const int wrow = row0 + wv*32;               // wave's 32 rows
    u16* hscr = lds + HS + wv*2048;
    const int rdswz = ((cl >> 2) & 3) << 4;      // scratch read XOR key

    // DMA chunk 0 -> slot0
#pragma unroll
    for (int i = 0; i < 4; ++i){
        int qq = (wv*4 + i)*64 + lane;
        { int r = qq >> 4, sp = qq & 15; int s = (sp & 8) | ((sp ^ r) & 7);
          dma16(BT1 + (size_t)r*128 + s*8, lds + qq*8); }
        { int r = qq >> 3, p = qq & 7; int s = (p ^ r) & 7;
          dma16(BT2 + (size_t)r*512 + s*8, lds + 8192 + qq*8); }
    }
    // A-fragments straight from global (xs is L2/L3-warm from decomp)
    bf16x8 afrag[2][4];
#pragma unroll
    for (int mt = 0; mt < 2; ++mt)
#pragma unroll
        for (int ks = 0; ks < 4; ++ks)
            afrag[mt][ks] = *(const bf16x8*)(xs + (size_t)(wrow + mt*16 + cl)*128 + ks*32 + quad*8);

    floatx4 Yacc[16];
#pragma unroll
    for (int i = 0; i < 16; ++i) Yacc[i] = (floatx4){0.f,0.f,0.f,0.f};

    __syncthreads();                             // chunk 0 landed

    for (int g = 0; g < 16; ++g){
        const int cur = (g & 1) ? SL1 : 0;
        const int nxt = (g & 1) ? 0 : SL1;
        if (g < 15){                             // DMA chunk g+1 (lands during this chunk)
            const u16* w1s = ((g+1) & 8) ? BT3 : BT1;
            const u16* w2s = ((g+1) & 8) ? BT4 : BT2;
            const int hb = ((g+1) & 7) * 64;
#pragma unroll
            for (int i = 0; i < 4; ++i){
                int qq = (wv*4 + i)*64 + lane;
                { int r = qq >> 4, sp = qq & 15; int s = (sp & 8) | ((sp ^ r) & 7);
                  dma16(w1s + (size_t)(hb + r)*128 + s*8, lds + nxt + qq*8); }
                { int r = qq >> 3, p = qq & 7; int s = (p ^ r) & 7;
                  dma16(w2s + (size_t)r*512 + hb + s*8, lds + nxt + 8192 + qq*8); }
            }
        }
        const float* ba = (g & 8) ? b21 : b11;
        const int hc = g & 7;

        // GEMM1: hacc[2][4] = afrag x W1c  (32 rows x 64 hidden, K=128)
        floatx4 hacc[8];
#pragma unroll
        for (int i = 0; i < 8; ++i) hacc[i] = (floatx4){0.f,0.f,0.f,0.f};
#pragma unroll
        for (int ks = 0; ks < 4; ++ks){
            bf16x8 bfr[4];
#pragma unroll
            for (int nt = 0; nt < 4; ++nt)
                bfr[nt] = *(const bf16x8*)(lds + cur + swz128(nt*16 + cl, ks*4 + quad));
#pragma unroll
            for (int mt = 0; mt < 2; ++mt)
#pragma unroll
                for (int nt = 0; nt < 4; ++nt)
                    hacc[mt*4+nt] = MFMA16(afrag[mt][ks], bfr[nt], hacc[mt*4+nt]);
        }
        // GELU -> private scratch (no barrier)
#pragma unroll
        for (int mt = 0; mt < 2; ++mt)
#pragma unroll
            for (int nt = 0; nt < 4; ++nt){
                floatx4 v = hacc[mt*4+nt];
                int h = nt*16 + cl;
                float bav = ba[hc*64 + h];
#pragma unroll
                for (int i = 0; i < 4; ++i){
                    int r = mt*16 + quad*4 + i;
                    hscr[r*64 + (h ^ (quad << 4))] = f2bf(fgelu(v[i] + bav));
                }
            }
        // GEMM2: Yacc += H x W2c  (32 rows x 128 n, K=64) -- reads own scratch
#pragma unroll
        for (int ks = 0; ks < 2; ++ks){
            bf16x8 a2[2];
#pragma unroll
            for (int mt = 0; mt < 2; ++mt)
                a2[mt] = *(const bf16x8*)(hscr + (mt*16 + cl)*64 + ((ks*32 + quad*8) ^ rdswz));
#pragma unroll
            for (int nt = 0; nt < 8; ++nt){
                bf16x8 b2 = *(const bf16x8*)(lds + cur + 8192 + swz64(nt*16 + cl, ks*4 + quad));
#pragma unroll
                for (int mt = 0; mt < 2; ++mt)
                    Yacc[mt*8+nt] = MFMA16(a2[mt], b2, Yacc[mt*8+nt]);
            }
        }
        __syncthreads();                         // slot reads done + DMA g+1 drained

        if (g == 7){
            // mlp0 -> mlp1 handoff: h1 = Y + b12, through private scratch, 2 passes
#pragma unroll
            for (int half = 0; half < 2; ++half){
#pragma unroll
                for (int mt = 0; mt < 2; ++mt)
#pragma unroll
                    for (int nt = 0; nt < 4; ++nt){
                        int ntg = half*4 + nt;
                        floatx4 v = Yacc[mt*8+ntg];
                        int c = ntg*16 + cl;
                        float bv = b12[c];
                        int h = nt*16 + cl;
#pragma unroll
                        for (int i = 0; i < 4; ++i){
                            int r = mt*16 + quad*4 + i;
                            hscr[r*64 + (h ^ (quad << 4))] = f2bf(v[i] + bv);
                        }
                    }
#pragma unroll
                for (int mt = 0; mt < 2; ++mt)
#pragma unroll
                    for (int k2 = 0; k2 < 2; ++k2)
                        afrag[mt][half*2 + k2] = *(const bf16x8*)(hscr + (mt*16 + cl)*64 + ((k2*32 + quad*8) ^ rdswz));
            }
#pragma unroll
            for (int i = 0; i < 16; ++i) Yacc[i] = (floatx4){0.f,0.f,0.f,0.f};
        }
    }

    // epilogue: h2 + b22 -> Afin[:, 512 + s*128 + n]  (row gr = bc*4+s)
#pragma unroll
    for (int mt = 0; mt < 2; ++mt)
#pragma unroll
        for (int nt = 0; nt < 8; ++nt){
            int c = nt*16 + cl;
            float bv = b22[c];
            floatx4 v = Yacc[mt*8+nt];
#pragma unroll
            for (int i = 0; i < 4; ++i){
                int gr = wrow + mt*16 + quad*4 + i;
                Afin[(size_t)(gr>>2)*1024 + 512 + (size_t)(gr&3)*128 + c] = f2bf(v[i] + bv);
            }
        }
}

// ---------------- final fused-head GEMM, DMA double-buffered, XCD-grouped ----------------
__global__ __launch_bounds__(256, 2) void head_gemm_k(
    const u16* __restrict__ A, const u16* __restrict__ BT,
    float* __restrict__ Cf,
    const float* __restrict__ bias, const float* __restrict__ bias2,
    const float* __restrict__ rw, const float* __restrict__ rb,
    const float2* __restrict__ stats)
{
    __shared__ u16 lds[32768];    // A slices @0,@8192 ; B slices @16384,@24576
    const int id = blockIdx.x;
    const int xcd = id & 7, slot = id >> 3;
    const int g8 = slot / 3, j = slot - g8*3;
    const int by = xcd + 8*g8;
    if (by >= 321) return;
    const int row0 = by * 128, col0 = j * 128;

    const int tid = threadIdx.x;
    const int lane = tid & 63;
    const int wv = tid >> 6;
    const int wm = wv & 1, wn = wv >> 1;
    const int quad = lane >> 4, cl = lane & 15;

    const int qbase = wv*4*64 + lane;

#pragma unroll
    for (int i = 0; i < 4; ++i){
        int qq = qbase + i*64;
        int r = qq >> 3, p = qq & 7; int s = (p ^ r) & 7;
        dma16(A  + (size_t)(row0 + r)*1024 + s*8, lds + qq*8);
        dma16(BT + (size_t)(col0 + r)*1024 + s*8, lds + 16384 + qq*8);
    }
    __syncthreads();

    floatx4 acc[16];
#pragma unroll
    for (int i = 0; i < 16; ++i) acc[i] = (floatx4){0.f,0.f,0.f,0.f};

    for (int it = 0; it < 16; ++it){
        const int cur = (it & 1) * 8192;
        if (it < 15){
            const int nxt = ((it+1) & 1) * 8192;
            const int k0 = (it+1) * 64;
#pragma unroll
            for (int i = 0; i < 4; ++i){
                int qq = qbase + i*64;
                int r = qq >> 3, p = qq & 7; int s = (p ^ r) & 7;
                dma16(A  + (size_t)(row0 + r)*1024 + k0 + s*8, lds + nxt + qq*8);
                dma16(BT + (size_t)(col0 + r)*1024 + k0 + s*8, lds + 16384 + nxt + qq*8);
            }
        }
#pragma unroll
        for (int kk = 0; kk < 2; ++kk){
            bf16x8 af[4], bfr[4];
#pragma unroll
            for (int mt = 0; mt < 4; ++mt) af[mt]  = *(const bf16x8*)(lds + cur + swz64(wm*64 + mt*16 + cl, kk*4 + quad));
#pragma unroll
            for (int nt = 0; nt < 4; ++nt) bfr[nt] = *(const bf16x8*)(lds + 16384 + cur + swz64(wn*64 + nt*16 + cl, kk*4 + quad));
#pragma unroll
            for (int mt = 0; mt < 4; ++mt)
#pragma unroll
                for (int nt = 0; nt < 4; ++nt)
                    acc[mt*4+nt] = MFMA16(af[mt], bfr[nt], acc[mt*4+nt]);
        }
        __syncthreads();
    }

#pragma unroll
    for (int mt = 0; mt < 4; ++mt)
#pragma unroll
        for (int nt = 0; nt < 4; ++nt){
            floatx4 v = acc[mt*4+nt];
            int gc = col0 + wn*64 + nt*16 + cl;
            if (gc >= PREDD) continue;
            float bsum = bias[gc] + bias2[gc];
#pragma unroll
            for (int i = 0; i < 4; ++i){
                int gr = row0 + wm*64 + mt*16 + quad*4 + i;
                float val = v[i] + bsum;
                int bv2 = gr / CC;
                int c  = gr - bv2*CC;
                val = (val - rb[c]) / (rw[c] + 1e-10f);
                float2 st = stats[gr];
                val = val*st.y + st.x;
                Cf[(size_t)bv2*(PREDD*CC) + (size_t)gc*CC + c] = val;
            }
        }
}

extern "C" void kernel_launch(void* const* d_in, const int* in_sizes, int n_in,
                              void* d_out, int out_size, void* d_ws, size_t ws_size,
                              hipStream_t stream)
{
    const float* x   = (const float*)d_in[0];
    const float* rvw = (const float*)d_in[1];
    const float* rvb = (const float*)d_in[2];
    const float* W11 = (const float*)d_in[3];
    const float* b11 = (const float*)d_in[4];
    const float* W12 = (const float*)d_in[5];
    const float* b12 = (const float*)d_in[6];
    const float* W21 = (const float*)d_in[7];
    const float* b21 = (const float*)d_in[8];
    const float* W22 = (const float*)d_in[9];
    const float* b22 = (const float*)d_in[10];
    const float* Wtr = (const float*)d_in[11];
    const float* btr = (const float*)d_in[12];
    const float* Wse = (const float*)d_in[13];
    const float* bse = (const float*)d_in[14];
    float* out = (float*)d_out;

    char* ws = (char*)d_ws;
    u16* BT1 = (u16*)(ws + 0);            //  512x128 bf16
    u16* BT2 = (u16*)(ws + 131072);       //  128x512
    u16* BT3 = (u16*)(ws + 262144);       //  512x128
    u16* BT4 = (u16*)(ws + 393216);       //  128x512
    u16* BT5 = (u16*)(ws + 524288);       //  384x1024
    float2* stats = (float2*)(ws + 1310720);      // 41088 x {mean,std}
    u16* Afin = (u16*)(ws + 1639424);     // concat-A [41088][1024]: trend | sea
    u16* xs   = (u16*)(ws + 85787648);    // [164352][128] split seasonal

    hipLaunchKernelGGL(prep_k, dim3(1536), dim3(256), 0, stream,
                       W11, W12, W21, W22, Wtr, Wse, BT1, BT2, BT3, BT4, BT5);
    hipLaunchKernelGGL(decomp_k, dim3(128*21), dim3(256), 0, stream,
                       x, rvw, rvb, Afin, xs, stats);
    hipLaunchKernelGGL(mlp_fused_k, dim3(1284), dim3(256), 0, stream,
                       xs, BT1, b11, BT2, b12, BT3, b21, BT4, b22, Afin);
    hipLaunchKernelGGL(head_gemm_k, dim3(984), dim3(256), 0, stream,
                       Afin, BT5, out, btr, bse, rvw, rvb, stats);
}